// Round 4
// baseline (68.794 us; speedup 1.0000x reference)
//
#include <hip/hip_runtime.h>
#include <math.h>

#define B_DIM 4
#define N_DIM 8192
#define C_DIM 256
#define LN_EPS 1e-5f
#define WSCALE 4096.0f
#define INV_WSCALE (1.0f/4096.0f)
#define SUM_SCALE 8192.0f
#define INV_SUM_SCALE (1.0f/8192.0f)
#define M_SCALE 67108864.0f        // 2^26
#define INV_M_SCALE (1.0f/67108864.0f)

typedef _Float16 f16x8 __attribute__((ext_vector_type(8)));
typedef float    f32x4 __attribute__((ext_vector_type(4)));

// ---- workspace layout (bytes) ----
// WT: 33 n-tiles x 8 kt x 64 lanes x 16B f16 fragments
#define WS_WT    0
#define WS_EXT   270336     // ext[256][16] f32 (extra B-tile source, pre-scaled)
#define WS_K1    286720     // K1h[8]
#define WS_K2    286752     // K2h[8]
#define WS_PART  286976     // part[512][256] f32
#define WS_QK    811264     // qk[4][256] f32

// ---------------------------------------------------------------------------
// k0a: build ext[k][0..15]: cols 0..7 = M[k,h]*2^26 (M = sum_{c in h} Wk[k,c]*Wq[c]*gamma[c]),
// col 8 = (sum_c Wk[k,c])*2^13, col 9 = (sum_c Wv[k,c])*2^13, cols 10..15 = 0.
// Also K1h = sum_d Wq*gamma, K2h = sum_d Wq*beta. grid 8 x 256, thread=(k,h).
// ---------------------------------------------------------------------------
__global__ void k0a_ext(const float* __restrict__ Wq,
                        const float* __restrict__ Wk,
                        const float* __restrict__ Wv,
                        const float* __restrict__ gamma,
                        const float* __restrict__ beta,
                        char* __restrict__ ws)
{
    const int gid = blockIdx.x * 256 + threadIdx.x;   // [0, 2048)
    const int k = gid >> 3;
    const int h = gid & 7;

    const float* __restrict__ wkrow = Wk + (size_t)k * C_DIM;
    const float* __restrict__ wvrow = Wv + (size_t)k * C_DIM;

    float m = 0.f, pk = 0.f, pv = 0.f;
    #pragma unroll 8
    for (int d = 0; d < 32; ++d) {
        const int c = h * 32 + d;
        const float wg = Wq[c] * gamma[c];
        const float a = wkrow[c];
        const float v = wvrow[c];
        m  = fmaf(a, wg, m);
        pk += a;
        pv += v;
    }
    // reduce pk, pv over the 8 h-lanes (h = lane&7)
    #pragma unroll
    for (int msk = 1; msk <= 4; msk <<= 1) {
        pk += __shfl_xor(pk, msk, 64);
        pv += __shfl_xor(pv, msk, 64);
    }
    float* __restrict__ ext = (float*)(ws + WS_EXT);
    ext[k * 16 + h] = m * M_SCALE;
    if (h == 0) ext[k * 16 + 8] = pk * SUM_SCALE;
    if (h == 1) ext[k * 16 + 9] = pv * SUM_SCALE;
    if (h >= 2) ext[k * 16 + 8 + h] = 0.f;            // cols 10..15

    if (blockIdx.x == 0 && threadIdx.x < 8) {
        const int hh = threadIdx.x;
        float k1v = 0.f, k2v = 0.f;
        for (int d = 0; d < 32; ++d) {
            const int c = hh * 32 + d;
            k1v = fmaf(Wq[c], gamma[c], k1v);
            k2v = fmaf(Wq[c], beta[c],  k2v);
        }
        ((float*)(ws + WS_K1))[hh] = k1v;
        ((float*)(ws + WS_K2))[hh] = k2v;
    }
}

// ---------------------------------------------------------------------------
// k0b: pack B-fragments. grid 33 blocks, block = one n-tile (16 cols x 256 k).
// B-frag (16x16x32): lane l holds B[k][n], n = nt*16+(l&15), k = kt*32+(l>>4)*8+j.
// ---------------------------------------------------------------------------
__global__ void k0b_pack(const float* __restrict__ Wk,
                         const float* __restrict__ Wv,
                         char* __restrict__ ws)
{
    __shared__ float Wl[256 * 16];     // Wl[k*16 + ci] = col (nt*16+ci), row k
    const int t  = threadIdx.x;
    const int nt = blockIdx.x;
    const int ci = t & 15;
    const int kk = t >> 4;             // 16 k-rows per iter

    const float* __restrict__ ext = (const float*)(ws + WS_EXT);
    #pragma unroll
    for (int i = 0; i < 16; ++i) {
        const int k = i * 16 + kk;
        float v;
        if (nt < 16)      v = Wk[(size_t)k * C_DIM + nt * 16 + ci] * WSCALE;
        else if (nt < 32) v = Wv[(size_t)k * C_DIM + (nt - 16) * 16 + ci] * WSCALE;
        else              v = ext[k * 16 + ci];       // pre-scaled
        Wl[k * 16 + ci] = v;
    }
    __syncthreads();

    f16x8* __restrict__ WT = (f16x8*)(ws + WS_WT);
    const int lane = t & 63;
    const int l15  = lane & 15;
    const int hi   = lane >> 4;
    for (int kt = (t >> 6); kt < 8; kt += 4) {
        f16x8 frag;
        #pragma unroll
        for (int j = 0; j < 8; ++j)
            frag[j] = (_Float16)Wl[(kt * 32 + hi * 8 + j) * 16 + l15];
        WT[(nt * 8 + kt) * 64 + lane] = frag;
    }
}

// ---------------------------------------------------------------------------
// K1: 64-row tile. C = [Uk|Uv] (f16 MFMA, f32 acc, x4096) stays in REGISTERS.
// Extra B-tile (nt=32, wave 0) yields T[r,h], row-sums sk, sv via MFMA.
// Epilogue: qkk/qvv shuffle-reduced from acc; s computed per row; qk partial
// = dot4(sr[h][rows], acc) reduced over row-groups. 4 waves n-split.
// ---------------------------------------------------------------------------
__global__ __launch_bounds__(256)
void k1_mfma_ln_reduce(const float* __restrict__ U,
                       const float* __restrict__ gamma,
                       const float* __restrict__ beta,
                       const char* __restrict__ ws_ro,
                       float* __restrict__ part)
{
    __shared__ char lds[41088];
    // A-tile f16 [64][256] swizzled: byte = row*512 + ((off) ^ ((row&7)<<4))   [0,32768)
    float*  __restrict__ T_lds = (float*)(lds + 32768);   // [64][8]
    float*  __restrict__ skv   = (float*)(lds + 34816);   // [64][2]
    float*  __restrict__ qq    = (float*)(lds + 35328);   // [4][64]
    float*  __restrict__ sraw  = (float*)(lds + 36352);   // [8][64]
    float*  __restrict__ sr    = (float*)(lds + 38400);   // [8][64]
    float2* __restrict__ vv    = (float2*)(lds + 40448);  // [64] {muv, rsv}
    float2* __restrict__ DS1   = (float2*)(lds + 40960);  // [8] {D, S1}

    const int t    = threadIdx.x;
    const int lane = t & 63;
    const int w    = t >> 6;
    const int l15  = lane & 15;
    const int rg   = lane >> 4;
    const int bid  = blockIdx.x;           // 512
    const int b    = bid >> 7;
    const int row0 = (bid & 127) * 64;

    // ---- stage U tile -> f16 swizzled LDS (convert in registers) ----
    {
        const float* __restrict__ Ub = U + ((size_t)b * N_DIM + row0) * C_DIM;
        #pragma unroll
        for (int i = 0; i < 8; ++i) {
            const int id = i * 256 + t;
            const int r  = id >> 5;
            const int kc = id & 31;
            const float4* __restrict__ src =
                (const float4*)(Ub + (size_t)r * C_DIM + kc * 8);
            const float4 v0 = src[0];
            const float4 v1 = src[1];
            f16x8 hv;
            hv[0] = (_Float16)v0.x; hv[1] = (_Float16)v0.y;
            hv[2] = (_Float16)v0.z; hv[3] = (_Float16)v0.w;
            hv[4] = (_Float16)v1.x; hv[5] = (_Float16)v1.y;
            hv[6] = (_Float16)v1.z; hv[7] = (_Float16)v1.w;
            const int byte = r * 512 + ((kc * 16) ^ ((r & 7) << 4));
            *(f16x8*)(lds + byte) = hv;
        }
    }
    __syncthreads();

    // ---- MFMA k-loop ----
    f32x4 acc[4][8];
    f32x4 acce[4];
    #pragma unroll
    for (int m = 0; m < 4; ++m) {
        #pragma unroll
        for (int j = 0; j < 8; ++j) acc[m][j] = (f32x4)0.0f;
        acce[m] = (f32x4)0.0f;
    }
    {
        const f16x8* __restrict__ WT = (const f16x8*)(ws_ro + WS_WT);
        const int swz = (l15 & 7) << 4;
        #pragma unroll 2
        for (int kt = 0; kt < 8; ++kt) {
            const int boff = ((kt * 64 + rg * 16) ^ swz) + l15 * 512;
            const f16x8 a0 = *(const f16x8*)(lds + boff);
            const f16x8 a1 = *(const f16x8*)(lds + boff + 8192);
            const f16x8 a2 = *(const f16x8*)(lds + boff + 16384);
            const f16x8 a3 = *(const f16x8*)(lds + boff + 24576);
            #pragma unroll
            for (int j = 0; j < 8; ++j) {
                const f16x8 bf = WT[(size_t)((w * 8 + j) * 8 + kt) * 64 + lane];
                acc[0][j] = __builtin_amdgcn_mfma_f32_16x16x32_f16(a0, bf, acc[0][j], 0, 0, 0);
                acc[1][j] = __builtin_amdgcn_mfma_f32_16x16x32_f16(a1, bf, acc[1][j], 0, 0, 0);
                acc[2][j] = __builtin_amdgcn_mfma_f32_16x16x32_f16(a2, bf, acc[2][j], 0, 0, 0);
                acc[3][j] = __builtin_amdgcn_mfma_f32_16x16x32_f16(a3, bf, acc[3][j], 0, 0, 0);
            }
            if (w == 0) {
                const f16x8 bf = WT[(size_t)(32 * 8 + kt) * 64 + lane];
                acce[0] = __builtin_amdgcn_mfma_f32_16x16x32_f16(a0, bf, acce[0], 0, 0, 0);
                acce[1] = __builtin_amdgcn_mfma_f32_16x16x32_f16(a1, bf, acce[1], 0, 0, 0);
                acce[2] = __builtin_amdgcn_mfma_f32_16x16x32_f16(a2, bf, acce[2], 0, 0, 0);
                acce[3] = __builtin_amdgcn_mfma_f32_16x16x32_f16(a3, bf, acce[3], 0, 0, 0);
            }
        }
    }

    // ---- wave 0: scatter extra-tile outputs (T, sk, sv) ----
    if (w == 0) {
        #pragma unroll
        for (int m = 0; m < 4; ++m)
            #pragma unroll
            for (int q = 0; q < 4; ++q) {
                const int row = m * 16 + rg * 4 + q;
                const float val = acce[m][q];
                if (l15 < 8)       T_lds[row * 8 + l15] = val * INV_M_SCALE;
                else if (l15 == 8) skv[row * 2 + 0] = val * INV_SUM_SCALE;
                else if (l15 == 9) skv[row * 2 + 1] = val * INV_SUM_SCALE;
            }
    }

    // ---- per-row sum of squares of this wave's 128 cols ----
    {
        float qp[16];
        #pragma unroll
        for (int m = 0; m < 4; ++m)
            #pragma unroll
            for (int q = 0; q < 4; ++q) {
                float s = 0.f;
                #pragma unroll
                for (int j = 0; j < 8; ++j) {
                    const float v = acc[m][j][q];
                    s = fmaf(v, v, s);
                }
                qp[m * 4 + q] = s;
            }
        #pragma unroll
        for (int i = 0; i < 16; ++i) {
            #pragma unroll
            for (int msk = 1; msk <= 8; msk <<= 1)
                qp[i] += __shfl_xor(qp[i], msk, 64);
        }
        if (l15 == 0) {
            #pragma unroll
            for (int m = 0; m < 4; ++m)
                #pragma unroll
                for (int q = 0; q < 4; ++q)
                    qq[w * 64 + m * 16 + rg * 4 + q] = qp[m * 4 + q];
        }
    }
    __syncthreads();

    // ---- per-row LN stats + s[r,h] ----
    if (t < 64) {
        const int r = t;
        const float sk = skv[r * 2 + 0];
        const float sv = skv[r * 2 + 1];
        const float qkk = (qq[0 * 64 + r] + qq[1 * 64 + r]) * (INV_WSCALE * INV_WSCALE);
        const float qvv = (qq[2 * 64 + r] + qq[3 * 64 + r]) * (INV_WSCALE * INV_WSCALE);
        const float muk  = sk * (1.f / 256.f);
        const float vark = qkk * (1.f / 256.f) - muk * muk;
        const float rsk  = 1.0f / sqrtf(vark + LN_EPS);
        const float muv  = sv * (1.f / 256.f);
        const float varv = qvv * (1.f / 256.f) - muv * muv;
        const float rsv  = 1.0f / sqrtf(varv + LN_EPS);
        vv[r] = make_float2(muv, rsv);
        const float* __restrict__ K1 = (const float*)(ws_ro + WS_K1);
        const float* __restrict__ K2 = (const float*)(ws_ro + WS_K2);
        #pragma unroll
        for (int h = 0; h < 8; ++h) {
            const float Tv = T_lds[r * 8 + h];
            const float s  = fmaf(rsk, Tv - muk * K1[h], K2[h]);
            sraw[h * 64 + r] = s;
            sr[h * 64 + r]   = s * rsv * INV_WSCALE;
        }
    }
    __syncthreads();

    if (t < 8) {
        const int h = t;
        float D = 0.f, S1 = 0.f;
        #pragma unroll 4
        for (int r = 0; r < 64; ++r) {
            const float s = sraw[h * 64 + r];
            const float2 mv = vv[r];
            D  = fmaf(s, mv.x * mv.y, D);
            S1 += s;
        }
        DS1[h] = make_float2(D, S1);
    }
    __syncthreads();

    // ---- v-waves: qk partial for this tile's 64 rows ----
    if (w >= 2) {
        #pragma unroll
        for (int j = 0; j < 8; ++j) {
            const int h = (w - 2) * 4 + (j >> 1);
            float p = 0.f;
            #pragma unroll
            for (int m = 0; m < 4; ++m) {
                const f32x4 s4 = *(const f32x4*)&sr[h * 64 + m * 16 + rg * 4];
                p = fmaf(s4[0], acc[m][j][0], p);
                p = fmaf(s4[1], acc[m][j][1], p);
                p = fmaf(s4[2], acc[m][j][2], p);
                p = fmaf(s4[3], acc[m][j][3], p);
            }
            p += __shfl_xor(p, 16, 64);
            p += __shfl_xor(p, 32, 64);
            if (rg == 0) {
                const int c = (w - 2) * 128 + j * 16 + l15;
                const float2 ds = DS1[h];
                part[(size_t)bid * 256 + c] =
                    fmaf(gamma[c], p - ds.x, beta[c] * ds.y);
            }
        }
    }
}

// ---------------------------------------------------------------------------
// K2: reduce 128 tile-partials per batch -> qk[b][c]
// grid 32: (b = blk>>3, col-group cg = blk&7)
// ---------------------------------------------------------------------------
__global__ void k2_reduce(const float* __restrict__ part, float* __restrict__ qk)
{
    __shared__ float red[8][32];
    const int t   = threadIdx.x;
    const int blk = blockIdx.x;
    const int b   = blk >> 3;
    const int cg  = blk & 7;
    const int c   = cg * 32 + (t & 31);
    const int seg = t >> 5;
    float s = 0.f;
    for (int i = seg * 16; i < seg * 16 + 16; ++i)
        s += part[((size_t)b * 128 + i) * 256 + c];
    red[seg][t & 31] = s;
    __syncthreads();
    if (t < 32) {
        float q = 0.f;
        #pragma unroll
        for (int sgi = 0; sgi < 8; ++sgi) q += red[sgi][t];
        qk[b * 256 + cg * 32 + t] = q;
    }
}

// ---------------------------------------------------------------------------
// K3: out[b,n,e*8+h] = X[b,n] * qk[b,h*32+e] / N   (33.5 MB write, BW-bound)
// ---------------------------------------------------------------------------
__global__ __launch_bounds__(256)
void k3_out(const float* __restrict__ X, const float* __restrict__ qk,
            float* __restrict__ out)
{
    __shared__ float qkp[256];   // permuted + prescaled: qkp[e*8+h]
    const int t = threadIdx.x;
    const int bid = blockIdx.x;
    const int b = bid >> 8;
    const int row0 = (bid & 255) * 32;

    {
        const int h = t & 7;
        const int e = t >> 3;
        qkp[t] = qk[b * 256 + h * 32 + e] * (1.0f / (float)N_DIM);
    }
    __syncthreads();

    const int c4 = (t & 63) * 4;
    const float4 q4 = *(const float4*)&qkp[c4];
    const int rl = t >> 6;

    for (int it = 0; it < 8; ++it) {
        const int row = row0 + it * 4 + rl;
        const float x = X[(size_t)b * N_DIM + row];
        float4 o;
        o.x = x * q4.x; o.y = x * q4.y; o.z = x * q4.z; o.w = x * q4.w;
        *(float4*)&out[((size_t)b * N_DIM + row) * C_DIM + c4] = o;
    }
}

// ---------------------------------------------------------------------------
extern "C" void kernel_launch(void* const* d_in, const int* in_sizes, int n_in,
                              void* d_out, int out_size, void* d_ws, size_t ws_size,
                              hipStream_t stream)
{
    const float* U     = (const float*)d_in[0];
    const float* X     = (const float*)d_in[1];
    const float* Wq    = (const float*)d_in[2];
    const float* Wk    = (const float*)d_in[3];
    const float* Wv    = (const float*)d_in[4];
    const float* gamma = (const float*)d_in[5];
    const float* beta  = (const float*)d_in[6];
    float* out = (float*)d_out;

    char* ws = (char*)d_ws;
    float* part = (float*)(ws + WS_PART);
    float* qk   = (float*)(ws + WS_QK);

    k0a_ext<<<8, 256, 0, stream>>>(Wq, Wk, Wv, gamma, beta, ws);
    k0b_pack<<<33, 256, 0, stream>>>(Wk, Wv, ws);
    k1_mfma_ln_reduce<<<512, 256, 0, stream>>>(U, gamma, beta, ws, part);
    k2_reduce<<<32, 256, 0, stream>>>(part, qk);
    k3_out<<<1024, 256, 0, stream>>>(X, qk, out);
}

// Round 5
// 54.945 us; speedup vs baseline: 1.2520x; 1.2520x over previous
//
#include <hip/hip_runtime.h>
#include <math.h>

#define B_DIM 4
#define N_DIM 8192
#define C_DIM 256
#define LN_EPS 1e-5f
#define WSCALE 4096.0f
#define INV_WSCALE (1.0f/4096.0f)
#define SUM_SCALE 8192.0f
#define INV_SUM_SCALE (1.0f/8192.0f)
#define M_SCALE 67108864.0f        // 2^26
#define INV_M_SCALE (1.0f/67108864.0f)

typedef _Float16 f16x8 __attribute__((ext_vector_type(8)));
typedef float    f32x4 __attribute__((ext_vector_type(4)));

// ---- workspace layout (bytes) ----
#define WS_WT    0          // 33 n-tiles x 8 kt x 64 lanes x 16B f16 fragments
#define WS_EXT   270336     // ext[256][16] f32 (extra B-tile source, pre-scaled)
#define WS_K1    286720     // K1h[8]
#define WS_K2    286752     // K2h[8]
#define WS_PART  286976     // part[512][256] f32
#define WS_QK    811264     // qk[4][256] f32

// ---------------------------------------------------------------------------
// k0a: ext[k][0..7] = M[k,h]*2^26 (M = sum_{c in h} Wk[k,c]*Wq[c]*gamma[c]),
// ext[k][8] = (sum_c Wk[k,c])*2^13, ext[k][9] = (sum_c Wv[k,c])*2^13, rest 0.
// K1h = sum_d Wq*gamma, K2h = sum_d Wq*beta.
// ---------------------------------------------------------------------------
__global__ void k0a_ext(const float* __restrict__ Wq,
                        const float* __restrict__ Wk,
                        const float* __restrict__ Wv,
                        const float* __restrict__ gamma,
                        const float* __restrict__ beta,
                        char* __restrict__ ws)
{
    const int gid = blockIdx.x * 256 + threadIdx.x;   // [0, 2048)
    const int k = gid >> 3;
    const int h = gid & 7;

    const float* __restrict__ wkrow = Wk + (size_t)k * C_DIM;
    const float* __restrict__ wvrow = Wv + (size_t)k * C_DIM;

    float m = 0.f, pk = 0.f, pv = 0.f;
    #pragma unroll 8
    for (int d = 0; d < 32; ++d) {
        const int c = h * 32 + d;
        const float wg = Wq[c] * gamma[c];
        const float a = wkrow[c];
        const float v = wvrow[c];
        m  = fmaf(a, wg, m);
        pk += a;
        pv += v;
    }
    #pragma unroll
    for (int msk = 1; msk <= 4; msk <<= 1) {
        pk += __shfl_xor(pk, msk, 64);
        pv += __shfl_xor(pv, msk, 64);
    }
    float* __restrict__ ext = (float*)(ws + WS_EXT);
    ext[k * 16 + h] = m * M_SCALE;
    if (h == 0) ext[k * 16 + 8] = pk * SUM_SCALE;
    if (h == 1) ext[k * 16 + 9] = pv * SUM_SCALE;
    if (h >= 2) ext[k * 16 + 8 + h] = 0.f;            // cols 10..15

    if (blockIdx.x == 0 && threadIdx.x < 8) {
        const int hh = threadIdx.x;
        float k1v = 0.f, k2v = 0.f;
        for (int d = 0; d < 32; ++d) {
            const int c = hh * 32 + d;
            k1v = fmaf(Wq[c], gamma[c], k1v);
            k2v = fmaf(Wq[c], beta[c],  k2v);
        }
        ((float*)(ws + WS_K1))[hh] = k1v;
        ((float*)(ws + WS_K2))[hh] = k2v;
    }
}

// ---------------------------------------------------------------------------
// k0b: pack B-fragments. grid 33, block = one 16-col n-tile x 256 k.
// B-frag (16x16x32): lane l holds B[k][n], n = nt*16+(l&15), k = kt*32+(l>>4)*8+j.
// ---------------------------------------------------------------------------
__global__ void k0b_pack(const float* __restrict__ Wk,
                         const float* __restrict__ Wv,
                         char* __restrict__ ws)
{
    __shared__ float Wl[256 * 16];
    const int t  = threadIdx.x;
    const int nt = blockIdx.x;
    const int ci = t & 15;
    const int kk = t >> 4;

    const float* __restrict__ ext = (const float*)(ws + WS_EXT);
    #pragma unroll
    for (int i = 0; i < 16; ++i) {
        const int k = i * 16 + kk;
        float v;
        if (nt < 16)      v = Wk[(size_t)k * C_DIM + nt * 16 + ci] * WSCALE;
        else if (nt < 32) v = Wv[(size_t)k * C_DIM + (nt - 16) * 16 + ci] * WSCALE;
        else              v = ext[k * 16 + ci];
        Wl[k * 16 + ci] = v;
    }
    __syncthreads();

    f16x8* __restrict__ WT = (f16x8*)(ws + WS_WT);
    const int lane = t & 63;
    const int l15  = lane & 15;
    const int hi   = lane >> 4;
    for (int kt = (t >> 6); kt < 8; kt += 4) {
        f16x8 frag;
        #pragma unroll
        for (int j = 0; j < 8; ++j)
            frag[j] = (_Float16)Wl[(kt * 32 + hi * 8 + j) * 16 + l15];
        WT[(nt * 8 + kt) * 64 + lane] = frag;
    }
}

// ---------------------------------------------------------------------------
// K1: 64-row tile, 512 threads / 8 waves. Wave w owns 64 output cols:
//   w<4: K cols [w*64, w*64+64)   (n-tiles nt = w*4+j)
//   w>=4: V cols [(w-4)*64, ...)  (n-tiles nt = 16+(w-4)*4+j)
// acc = 4 m-tiles x 4 j x f32x4 = 64 VGPR. Wave 0 also runs the ext tile
// (nt=32) giving T[r,h], row-sums sk, sv via MFMA. C never leaves registers.
// ---------------------------------------------------------------------------
__global__ __launch_bounds__(512, 4)
void k1_mfma_ln_reduce(const float* __restrict__ U,
                       const float* __restrict__ gamma,
                       const float* __restrict__ beta,
                       const char* __restrict__ ws_ro,
                       float* __restrict__ part)
{
    __shared__ char lds[39744];
    // A-tile f16 [64][256] swizzled: byte = row*512 + (off ^ ((row&7)<<4))  [0,32768)
    float*  __restrict__ T_lds = (float*)(lds + 32768);   // [64][9] padded
    float*  __restrict__ sk_a  = (float*)(lds + 35072);   // [64]
    float*  __restrict__ sv_a  = (float*)(lds + 35328);   // [64]
    float*  __restrict__ qq    = (float*)(lds + 35584);   // [8][64]
    float*  __restrict__ sr    = (float*)(lds + 37632);   // [8][64]
    float2* __restrict__ DS1   = (float2*)(lds + 39680);  // [8] {D, S1}

    const int t    = threadIdx.x;
    const int lane = t & 63;
    const int w    = t >> 6;
    const int l15  = lane & 15;
    const int rg   = lane >> 4;
    const int bid  = blockIdx.x;           // 512
    const int b    = bid >> 7;
    const int row0 = (bid & 127) * 64;

    // ---- stage U tile -> f16 swizzled LDS ----
    {
        const float* __restrict__ Ub = U + ((size_t)b * N_DIM + row0) * C_DIM;
        #pragma unroll
        for (int i = 0; i < 4; ++i) {
            const int id = i * 512 + t;
            const int r  = id >> 5;
            const int kc = id & 31;
            const float4* __restrict__ src =
                (const float4*)(Ub + (size_t)r * C_DIM + kc * 8);
            const float4 v0 = src[0];
            const float4 v1 = src[1];
            f16x8 hv;
            hv[0] = (_Float16)v0.x; hv[1] = (_Float16)v0.y;
            hv[2] = (_Float16)v0.z; hv[3] = (_Float16)v0.w;
            hv[4] = (_Float16)v1.x; hv[5] = (_Float16)v1.y;
            hv[6] = (_Float16)v1.z; hv[7] = (_Float16)v1.w;
            *(f16x8*)(lds + r * 512 + ((kc * 16) ^ ((r & 7) << 4))) = hv;
        }
    }
    __syncthreads();

    // ---- MFMA k-loop ----
    f32x4 acc[4][4];
    f32x4 acce[4];
    #pragma unroll
    for (int m = 0; m < 4; ++m) {
        #pragma unroll
        for (int j = 0; j < 4; ++j) acc[m][j] = (f32x4)0.0f;
        acce[m] = (f32x4)0.0f;
    }
    {
        const f16x8* __restrict__ WT = (const f16x8*)(ws_ro + WS_WT);
        const int swz = (l15 & 7) << 4;
        const int nt0 = (w < 4) ? (w * 4) : (16 + (w - 4) * 4);
        for (int kt = 0; kt < 8; ++kt) {
            const int boff = ((kt * 64 + rg * 16) ^ swz) + l15 * 512;
            const f16x8 a0 = *(const f16x8*)(lds + boff);
            const f16x8 a1 = *(const f16x8*)(lds + boff + 8192);
            const f16x8 a2 = *(const f16x8*)(lds + boff + 16384);
            const f16x8 a3 = *(const f16x8*)(lds + boff + 24576);
            #pragma unroll
            for (int j = 0; j < 4; ++j) {
                const f16x8 bf = WT[(size_t)((nt0 + j) * 8 + kt) * 64 + lane];
                acc[0][j] = __builtin_amdgcn_mfma_f32_16x16x32_f16(a0, bf, acc[0][j], 0, 0, 0);
                acc[1][j] = __builtin_amdgcn_mfma_f32_16x16x32_f16(a1, bf, acc[1][j], 0, 0, 0);
                acc[2][j] = __builtin_amdgcn_mfma_f32_16x16x32_f16(a2, bf, acc[2][j], 0, 0, 0);
                acc[3][j] = __builtin_amdgcn_mfma_f32_16x16x32_f16(a3, bf, acc[3][j], 0, 0, 0);
            }
            if (w == 0) {
                const f16x8 bf = WT[(size_t)(32 * 8 + kt) * 64 + lane];
                acce[0] = __builtin_amdgcn_mfma_f32_16x16x32_f16(a0, bf, acce[0], 0, 0, 0);
                acce[1] = __builtin_amdgcn_mfma_f32_16x16x32_f16(a1, bf, acce[1], 0, 0, 0);
                acce[2] = __builtin_amdgcn_mfma_f32_16x16x32_f16(a2, bf, acce[2], 0, 0, 0);
                acce[3] = __builtin_amdgcn_mfma_f32_16x16x32_f16(a3, bf, acce[3], 0, 0, 0);
            }
        }
    }

    // ---- wave 0: scatter extra-tile outputs (T, sk, sv) ----
    if (w == 0) {
        #pragma unroll
        for (int m = 0; m < 4; ++m)
            #pragma unroll
            for (int q = 0; q < 4; ++q) {
                const int row = m * 16 + rg * 4 + q;
                const float val = acce[m][q];
                if (l15 < 8)       T_lds[row * 9 + l15] = val * INV_M_SCALE;
                else if (l15 == 8) sk_a[row] = val * INV_SUM_SCALE;
                else if (l15 == 9) sv_a[row] = val * INV_SUM_SCALE;
            }
    }

    // ---- per-row sum of squares of this wave's 64 cols ----
    {
        float qp[16];
        #pragma unroll
        for (int m = 0; m < 4; ++m)
            #pragma unroll
            for (int q = 0; q < 4; ++q) {
                float s = 0.f;
                #pragma unroll
                for (int j = 0; j < 4; ++j) {
                    const float v = acc[m][j][q];
                    s = fmaf(v, v, s);
                }
                qp[m * 4 + q] = s;
            }
        #pragma unroll
        for (int i = 0; i < 16; ++i) {
            #pragma unroll
            for (int msk = 1; msk <= 8; msk <<= 1)
                qp[i] += __shfl_xor(qp[i], msk, 64);
        }
        if (l15 == 0) {
            #pragma unroll
            for (int m = 0; m < 4; ++m)
                #pragma unroll
                for (int q = 0; q < 4; ++q)
                    qq[w * 64 + m * 16 + rg * 4 + q] = qp[m * 4 + q];
        }
    }
    __syncthreads();

    // ---- stats + s[r,h] + D/S1 (wave 0 only: t<64, full wave) ----
    if (t < 64) {
        const int r = t;
        const float sk = sk_a[r];
        const float sv = sv_a[r];
        const float qkk = (qq[0 * 64 + r] + qq[1 * 64 + r] +
                           qq[2 * 64 + r] + qq[3 * 64 + r]) * (INV_WSCALE * INV_WSCALE);
        const float qvv = (qq[4 * 64 + r] + qq[5 * 64 + r] +
                           qq[6 * 64 + r] + qq[7 * 64 + r]) * (INV_WSCALE * INV_WSCALE);
        const float muk  = sk * (1.f / 256.f);
        const float vark = qkk * (1.f / 256.f) - muk * muk;
        const float rsk  = 1.0f / sqrtf(vark + LN_EPS);
        const float muv  = sv * (1.f / 256.f);
        const float varv = qvv * (1.f / 256.f) - muv * muv;
        const float rsv  = 1.0f / sqrtf(varv + LN_EPS);
        const float wvr  = muv * rsv;
        const float* __restrict__ K1 = (const float*)(ws_ro + WS_K1);
        const float* __restrict__ K2 = (const float*)(ws_ro + WS_K2);
        #pragma unroll
        for (int h = 0; h < 8; ++h) {
            const float s = fmaf(rsk, T_lds[r * 9 + h] - muk * K1[h], K2[h]);
            sr[h * 64 + r] = s * rsv * INV_WSCALE;
            float d = s * wvr, s1 = s;
            #pragma unroll
            for (int msk = 1; msk <= 32; msk <<= 1) {
                d  += __shfl_xor(d,  msk, 64);
                s1 += __shfl_xor(s1, msk, 64);
            }
            if (r == h) DS1[h] = make_float2(d, s1);
        }
    }
    __syncthreads();

    // ---- V-waves: qk partial for this tile ----
    if (w >= 4) {
        #pragma unroll
        for (int j = 0; j < 4; ++j) {
            const int h = (w - 4) * 2 + (j >> 1);
            float p = 0.f;
            #pragma unroll
            for (int m = 0; m < 4; ++m) {
                const f32x4 s4 = *(const f32x4*)&sr[h * 64 + m * 16 + rg * 4];
                p = fmaf(s4[0], acc[m][j][0], p);
                p = fmaf(s4[1], acc[m][j][1], p);
                p = fmaf(s4[2], acc[m][j][2], p);
                p = fmaf(s4[3], acc[m][j][3], p);
            }
            p += __shfl_xor(p, 16, 64);
            p += __shfl_xor(p, 32, 64);
            if (rg == 0) {
                const int c = (w - 4) * 64 + j * 16 + l15;
                const float2 ds = DS1[h];
                part[(size_t)bid * 256 + c] =
                    fmaf(gamma[c], p - ds.x, beta[c] * ds.y);
            }
        }
    }
}

// ---------------------------------------------------------------------------
// K2: reduce 128 tile-partials per batch -> qk[b][c]
// ---------------------------------------------------------------------------
__global__ void k2_reduce(const float* __restrict__ part, float* __restrict__ qk)
{
    __shared__ float red[8][32];
    const int t   = threadIdx.x;
    const int blk = blockIdx.x;
    const int b   = blk >> 3;
    const int cg  = blk & 7;
    const int c   = cg * 32 + (t & 31);
    const int seg = t >> 5;
    float s = 0.f;
    for (int i = seg * 16; i < seg * 16 + 16; ++i)
        s += part[((size_t)b * 128 + i) * 256 + c];
    red[seg][t & 31] = s;
    __syncthreads();
    if (t < 32) {
        float q = 0.f;
        #pragma unroll
        for (int sgi = 0; sgi < 8; ++sgi) q += red[sgi][t];
        qk[b * 256 + cg * 32 + t] = q;
    }
}

// ---------------------------------------------------------------------------
// K3: out[b,n,e*8+h] = X[b,n] * qk[b,h*32+e] / N
// ---------------------------------------------------------------------------
__global__ __launch_bounds__(256)
void k3_out(const float* __restrict__ X, const float* __restrict__ qk,
            float* __restrict__ out)
{
    __shared__ float qkp[256];
    const int t = threadIdx.x;
    const int bid = blockIdx.x;
    const int b = bid >> 8;
    const int row0 = (bid & 255) * 32;

    {
        const int h = t & 7;
        const int e = t >> 3;
        qkp[t] = qk[b * 256 + h * 32 + e] * (1.0f / (float)N_DIM);
    }
    __syncthreads();

    const int c4 = (t & 63) * 4;
    const float4 q4 = *(const float4*)&qkp[c4];
    const int rl = t >> 6;

    for (int it = 0; it < 8; ++it) {
        const int row = row0 + it * 4 + rl;
        const float x = X[(size_t)b * N_DIM + row];
        float4 o;
        o.x = x * q4.x; o.y = x * q4.y; o.z = x * q4.z; o.w = x * q4.w;
        *(float4*)&out[((size_t)b * N_DIM + row) * C_DIM + c4] = o;
    }
}

// ---------------------------------------------------------------------------
extern "C" void kernel_launch(void* const* d_in, const int* in_sizes, int n_in,
                              void* d_out, int out_size, void* d_ws, size_t ws_size,
                              hipStream_t stream)
{
    const float* U     = (const float*)d_in[0];
    const float* X     = (const float*)d_in[1];
    const float* Wq    = (const float*)d_in[2];
    const float* Wk    = (const float*)d_in[3];
    const float* Wv    = (const float*)d_in[4];
    const float* gamma = (const float*)d_in[5];
    const float* beta  = (const float*)d_in[6];
    float* out = (float*)d_out;

    char* ws = (char*)d_ws;
    float* part = (float*)(ws + WS_PART);
    float* qk   = (float*)(ws + WS_QK);

    k0a_ext<<<8, 256, 0, stream>>>(Wq, Wk, Wv, gamma, beta, ws);
    k0b_pack<<<33, 256, 0, stream>>>(Wk, Wv, ws);
    k1_mfma_ln_reduce<<<512, 512, 0, stream>>>(U, gamma, beta, ws, part);
    k2_reduce<<<32, 256, 0, stream>>>(part, qk);
    k3_out<<<1024, 256, 0, stream>>>(X, qk, out);
}